// Round 2
// baseline (138.215 us; speedup 1.0000x reference)
//
#include <hip/hip_runtime.h>
#include <math.h>

// MarginDevianceLoss: N=4096, D=256, K=8, targets = i/8.
// Outputs: [loss, prec, pos_d, neg_d] fp32.
//
// R17b (R17 resubmit after infra failure; + y0/y1 latency split in rowstats):
// eliminate the pass-1 stats GEMM (one of two ~40us 4096x4096x256 GEMMs)
// via the Gram factorization:
//   S_i  = x_i . s          with s = sum_j x_j            (256-vector)
//   SQ_i = x_i^T G x_i      with G = X^T X                (256x256)
//   classSim = 8x8 diagonal blocks (8 MFMAs per 16-row tile)
// G is built from the SAME RNE-bf16-rounded x as Xf and stored as a
// hi/lo bf16 split in MFMA B-fragment layout, so the row-stats kernel's
// Y = Xb @ (Ghi+Glo) matches fp32-G precision (~2^-18 rel).
// Dispatches: convert -> gram -> rowstats -> lossGemm -> finalAB.
// The loss GEMM keeps R16's proven loop (NT=4, 64 rows/wave, glds-staged
// B, branchless filter + poly-softplus); its prologue shrinks to 2
// loads/row (inter/thresh precomputed once in rowstats instead of
// 32x-redundantly per j-block).
// Kept lessons: frag-major bf16 Xf + glds B-staging (R11); no inline fp32
// staging (R12); no big atomic fan-in / grid barriers (R7/R13).

#define NROWS 4096
#define DIM   256
#define KCLS  8
#define NJB   32     // j-blocks = partials per row (loss gemm)
#define NT    4      // i-tiles per wave (loss gemm)

typedef __bf16 bf16x8 __attribute__((ext_vector_type(8)));
typedef float  f32x4  __attribute__((ext_vector_type(4)));

// log(1+exp(z)) = max(z,0) + ln2 * log2(1 + exp2(-|z|*log2e));
// log2(1+u), u in (0,1], quartic fit (abs err <= ~4e-4).
__device__ __forceinline__ float softplus_poly(float z) {
    float u = __builtin_exp2f(-1.4426950408889634f * __builtin_fabsf(z));
    float p = u * (1.4426950f + u * (-0.6949650f + u * (0.3454302f + u * -0.0931600f)));
    return fmaf(p, 0.6931471805599453f, fmaxf(z, 0.f));
}

__device__ __forceinline__ unsigned int pack_bf2(float a, float b) {
    unsigned int ua = __float_as_uint(a);
    unsigned int ub = __float_as_uint(b);
    ua = (ua + 0x7FFFu + ((ua >> 16) & 1u)) >> 16;   // RNE
    ub = (ub + 0x7FFFu + ((ub >> 16) & 1u)) >> 16;
    return ua | (ub << 16);
}

__device__ __forceinline__ void glds16(const unsigned short* g, unsigned short* l) {
    // HW: each lane reads 16 B at its own g; LDS dest = uniform l + lane*16.
    __builtin_amdgcn_global_load_lds(
        (const __attribute__((address_space(1))) void*)g,
        (__attribute__((address_space(3))) void*)l, 16, 0, 0);
}

// X (fp32 row-major) -> Xf (bf16 fragment-major):
// Xf[((tile*8 + kf)*64 + lane)*8 + e] = X[tile*16 + (lane&15)][kf*32 + (lane>>4)*8 + e]
// Also zeroes the colsum accumulator (used next dispatch) and the finalAB
// done-counter (used 4 dispatches later).
__global__ __launch_bounds__(256)
void convert_kernel(const float* __restrict__ X, unsigned short* __restrict__ Xf,
                    unsigned int* __restrict__ counter, float* __restrict__ sCol)
{
    int v = blockIdx.x * 256 + threadIdx.x;    // 131072 fragment-slices of 16 B
    if (v == 0) *counter = 0u;
    if (v < 256) sCol[v] = 0.f;
    int tile = v >> 9;
    int kf   = (v >> 6) & 7;
    int lane = v & 63;
    int row  = tile * 16 + (lane & 15);
    int c4   = kf * 8 + (lane >> 4) * 2;       // col/4
    const float4* X4 = reinterpret_cast<const float4*>(X);
    float4 a = X4[row * 64 + c4];
    float4 b = X4[row * 64 + c4 + 1];
    uint4 o;
    o.x = pack_bf2(a.x, a.y);
    o.y = pack_bf2(a.z, a.w);
    o.z = pack_bf2(b.x, b.y);
    o.w = pack_bf2(b.z, b.w);
    reinterpret_cast<uint4*>(Xf)[v] = o;
}

// G = Xb^T Xb (256x256, fp32 accum via MFMA), written as hi/lo bf16 split in
// B-fragment-major layout:
//   Gf[((dt*8 + kf)*64 + lane)*8 + e] = G[kf*32 + (lane>>4)*8 + e][dt*16 + (lane&15)]
// Grid (8,8): block = 32x32 G region; 4 waves split K=4096 in quarters,
// LDS-reduce, then each thread owns one (tile,lane) cell (4 r-values).
// blockIdx.y==0 blocks also accumulate colsum s via 1K atomics.
__global__ __launch_bounds__(256)
void gram_kernel(const float* __restrict__ X,
                 unsigned short* __restrict__ Gfhi,
                 unsigned short* __restrict__ Gflo,
                 float* __restrict__ sCol)
{
    __shared__ float red[4][4][64][4];         // 16 KB
    const int t    = threadIdx.x;
    const int lane = t & 63;
    const int w    = t >> 6;
    const int q    = lane >> 4;
    const int n    = lane & 15;
    const int c0   = blockIdx.x * 32;
    const int d0   = blockIdx.y * 32;

    f32x4 ac[2][2];
    #pragma unroll
    for (int ct = 0; ct < 2; ++ct)
        #pragma unroll
        for (int dt = 0; dt < 2; ++dt)
            ac[ct][dt] = {0.f, 0.f, 0.f, 0.f};
    float sacc0 = 0.f, sacc1 = 0.f;

    const float* base = X + (w * 1024 + q * 8) * 256;
    for (int ks = 0; ks < 32; ++ks) {
        bf16x8 af[2], bfr[2];
        #pragma unroll
        for (int ct = 0; ct < 2; ++ct) {
            float v[8];
            #pragma unroll
            for (int e = 0; e < 8; ++e) v[e] = base[e * 256 + c0 + ct * 16 + n];
            if (blockIdx.y == 0) {
                float sv = ((v[0]+v[1])+(v[2]+v[3])) + ((v[4]+v[5])+(v[6]+v[7]));
                if (ct == 0) sacc0 += sv; else sacc1 += sv;
            }
            uint4 u;
            u.x = pack_bf2(v[0], v[1]); u.y = pack_bf2(v[2], v[3]);
            u.z = pack_bf2(v[4], v[5]); u.w = pack_bf2(v[6], v[7]);
            af[ct] = *reinterpret_cast<bf16x8*>(&u);
        }
        #pragma unroll
        for (int dt = 0; dt < 2; ++dt) {
            float v[8];
            #pragma unroll
            for (int e = 0; e < 8; ++e) v[e] = base[e * 256 + d0 + dt * 16 + n];
            uint4 u;
            u.x = pack_bf2(v[0], v[1]); u.y = pack_bf2(v[2], v[3]);
            u.z = pack_bf2(v[4], v[5]); u.w = pack_bf2(v[6], v[7]);
            bfr[dt] = *reinterpret_cast<bf16x8*>(&u);
        }
        #pragma unroll
        for (int ct = 0; ct < 2; ++ct)
            #pragma unroll
            for (int dt = 0; dt < 2; ++dt)
                ac[ct][dt] = __builtin_amdgcn_mfma_f32_16x16x32_bf16(af[ct], bfr[dt], ac[ct][dt], 0, 0, 0);
        base += 32 * 256;
    }

    if (blockIdx.y == 0) {
        sacc0 += __shfl_xor(sacc0, 16); sacc0 += __shfl_xor(sacc0, 32);
        sacc1 += __shfl_xor(sacc1, 16); sacc1 += __shfl_xor(sacc1, 32);
        if (lane < 16) {
            atomicAdd(&sCol[c0 + lane], sacc0);
            atomicAdd(&sCol[c0 + 16 + lane], sacc1);
        }
    }

    #pragma unroll
    for (int ct = 0; ct < 2; ++ct)
        #pragma unroll
        for (int dt = 0; dt < 2; ++dt)
            *reinterpret_cast<f32x4*>(&red[w][ct * 2 + dt][lane][0]) = ac[ct][dt];
    __syncthreads();

    const int tile = t >> 6;                   // re-partition: thread -> (tile, cell)
    const int ln   = t & 63;
    float v[4];
    #pragma unroll
    for (int r = 0; r < 4; ++r)
        v[r] = (red[0][tile][ln][r] + red[1][tile][ln][r])
             + (red[2][tile][ln][r] + red[3][tile][ln][r]);
    const int ct = tile >> 1, dt = tile & 1;
    const int qq = ln >> 4,  nn = ln & 15;
    // C-layout cell: G[c][d], c = c0+ct*16+qq*4+r, d = d0+dt*16+nn.
    // Frag dest: kf = blockIdx.x (cb), slot = (ct*2 + qq>>1)*16 + nn, e = (qq&1)*4 + r.
    float hi[4], lo[4];
    #pragma unroll
    for (int r = 0; r < 4; ++r) {
        unsigned int uv = __float_as_uint(v[r]);
        unsigned int h  = (uv + 0x7FFFu + ((uv >> 16) & 1u)) & 0xFFFF0000u;
        hi[r] = __uint_as_float(h);
        lo[r] = v[r] - hi[r];                  // exact
    }
    const int f    = (blockIdx.y * 2 + dt) * 8 + blockIdx.x;
    const int slot = (ct * 2 + (qq >> 1)) * 16 + nn;
    const int hw   = (f * 64 + slot) * 8 + (qq & 1) * 4;   // halfword offset, 8B-aligned
    uint2 ho, lv;
    ho.x = pack_bf2(hi[0], hi[1]); ho.y = pack_bf2(hi[2], hi[3]);   // exact repack
    lv.x = pack_bf2(lo[0], lo[1]); lv.y = pack_bf2(lo[2], lo[3]);
    *reinterpret_cast<uint2*>(&Gfhi[hw]) = ho;
    *reinterpret_cast<uint2*>(&Gflo[hw]) = lv;
}

// Per-row stats WITHOUT the NxN GEMM. Grid 64 x 256 thr; wave w -> i-tile
// bx*4+w (16 rows). classSim = mfma(afrag, afrag) diag blocks; Y = Xb@(Ghi+Glo)
// consumed on the fly: SQ_i = sum_d Y[i][d]*x[i][d], S_i = sum_d s[d]*x[i][d].
// hi/lo chains kept in separate accumulators (y0/y1) to halve the serial
// MFMA dependency (this kernel is 1 wave/CU -> latency-bound).
// Then 1 thread/row computes inter/thresh/posLoss/psum/nsum (single writer).
__global__ __launch_bounds__(256)
void rowstats_kernel(const float* __restrict__ X,
                     const unsigned short* __restrict__ Xf,
                     const unsigned short* __restrict__ Gfhi,
                     const unsigned short* __restrict__ Gflo,
                     const float* __restrict__ sCol,
                     float* __restrict__ c40A, float* __restrict__ threshA,
                     float* __restrict__ posLossA,
                     float* __restrict__ rowPsum, float* __restrict__ rowNsum)
{
    __shared__ float csL[64][8];
    __shared__ float sqL[64], smL[64];
    const int t    = threadIdx.x;
    const int lane = t & 63;
    const int w    = t >> 6;
    const int q    = lane >> 4;
    const int n    = lane & 15;
    const int it   = blockIdx.x * 4 + w;
    const int i0   = it * 16;

    bf16x8 afrag[8];
    const unsigned short* ap = Xf + (size_t)it * 8 * 512 + lane * 8;
    #pragma unroll
    for (int kf = 0; kf < 8; ++kf)
        afrag[kf] = *reinterpret_cast<const bf16x8*>(ap + kf * 512);

    // classSim: self-tile sim (afrag works as both A and B fragment)
    f32x4 cac = {0.f, 0.f, 0.f, 0.f};
    #pragma unroll
    for (int kf = 0; kf < 8; ++kf)
        cac = __builtin_amdgcn_mfma_f32_16x16x32_bf16(afrag[kf], afrag[kf], cac, 0, 0, 0);
    #pragma unroll
    for (int r = 0; r < 4; ++r) {
        int row = q * 4 + r;
        if (((row ^ n) >> 3) == 0) csL[w * 16 + row][n & 7] = cac[r];
    }

    float sqa[4] = {0.f, 0.f, 0.f, 0.f};
    float sma[4] = {0.f, 0.f, 0.f, 0.f};
    #pragma unroll 1
    for (int jt = 0; jt < 16; ++jt) {
        const unsigned short* gp = Gfhi + (size_t)jt * 8 * 512 + lane * 8;
        const unsigned short* lp = Gflo + (size_t)jt * 8 * 512 + lane * 8;
        f32x4 y0 = {0.f, 0.f, 0.f, 0.f};
        f32x4 y1 = {0.f, 0.f, 0.f, 0.f};
        #pragma unroll
        for (int kf = 0; kf < 8; ++kf) {
            bf16x8 gh = *reinterpret_cast<const bf16x8*>(gp + kf * 512);
            bf16x8 gl = *reinterpret_cast<const bf16x8*>(lp + kf * 512);
            y0 = __builtin_amdgcn_mfma_f32_16x16x32_bf16(afrag[kf], gh, y0, 0, 0, 0);
            y1 = __builtin_amdgcn_mfma_f32_16x16x32_bf16(afrag[kf], gl, y1, 0, 0, 0);
        }
        int d = jt * 16 + n;
        float sd = sCol[d];
        #pragma unroll
        for (int r = 0; r < 4; ++r) {
            float xl = X[(i0 + q * 4 + r) * 256 + d];
            sqa[r] = fmaf(y0[r] + y1[r], xl, sqa[r]);
            sma[r] = fmaf(sd, xl, sma[r]);
        }
    }
    #pragma unroll
    for (int r = 0; r < 4; ++r) {
        float a = sqa[r], b = sma[r];
        #pragma unroll
        for (int m = 8; m >= 1; m >>= 1) {
            a += __shfl_xor(a, m);
            b += __shfl_xor(b, m);
        }
        if (n == 0) { sqL[w * 16 + q * 4 + r] = a; smL[w * 16 + q * 4 + r] = b; }
    }
    __syncthreads();

    if (t < 64) {
        const int i = blockIdx.x * 64 + t;
        const int self = i & 7;
        float cs[KCLS];
        #pragma unroll
        for (int m = 0; m < KCLS; ++m) cs[m] = csL[t][m];
        float sii = cs[self];
        float psum = 0.f, psq = 0.f, pmin = 1e30f;
        #pragma unroll
        for (int m = 0; m < KCLS; ++m) {
            if (m != self) {
                psum += cs[m];
                psq  += cs[m] * cs[m];
                pmin  = fminf(pmin, cs[m]);
            }
        }
        const float p = (float)(KCLS - 1);            // 7
        const float mneg = (float)(NROWS - KCLS);     // 4088
        float S  = smL[t];
        float SQ = sqL[t];
        float nsum = S - psum - sii;
        float nsq  = SQ - psq - sii * sii;
        float pmean = psum / p;
        float pstd  = sqrtf(fmaxf(psq / p - pmean * pmean, 0.f));
        float nmean = nsum / mneg;
        float nstd  = sqrtf(fmaxf(nsq / mneg - nmean * nmean, 0.f));
        float inter = 0.8f * (nstd * pmean + pstd * nmean) / (pstd + nstd) + 0.1f;
        float pl = 0.f;
        #pragma unroll
        for (int m = 0; m < KCLS; ++m) {
            if (m != self) pl += softplus_poly(-10.f * (cs[m] - inter));
        }
        c40A[i]     = -40.f * inter;
        threshA[i]  = pmin - 0.05f;
        posLossA[i] = pl * (0.2f / p);
        rowPsum[i]  = psum;
        rowNsum[i]  = nsum;
    }
}

// Loss GEMM (R16 loop verbatim). Grid (16,32). Block: 4 waves; wave w ->
// i-tiles [bx*16+w*4, +4) (64 rows, A cached in regs). All waves sweep
// j-tiles [by*8,+8); B staged via LDS (global_load_lds, double-buffered).
// Prologue just loads precomputed -40*inter / thresh per row.
__global__ __launch_bounds__(256)
void loss_gemm_kernel(const unsigned short* __restrict__ Xf,
                      const float* __restrict__ c40A,
                      const float* __restrict__ threshA,
                      float* __restrict__ cntPart,
                      float* __restrict__ nlsPart)
{
    __shared__ __align__(16) unsigned short Bs[2][8][512];   // 2 x 8 KB
    __shared__ float c40L[256], threshL[256];

    const int t    = threadIdx.x;
    const int lane = t & 63;
    const int wave = t >> 6;
    const int quad = lane >> 4;
    const int n16  = lane & 15;
    const int it0  = blockIdx.x * 16 + wave * NT;
    const int i0   = it0 * 16;
    const int j0   = blockIdx.y * 128;
    const int jt0  = blockIdx.y * 8;

    // A fragments: NT i-tiles x 8 k-frags, coalesced 1-KB global loads
    bf16x8 afrag[NT][8];
    #pragma unroll
    for (int tt = 0; tt < NT; ++tt) {
        const unsigned short* ap = Xf + ((size_t)(it0 + tt) * 8) * 512 + lane * 8;
        #pragma unroll
        for (int kf = 0; kf < 8; ++kf)
            afrag[tt][kf] = *reinterpret_cast<const bf16x8*>(ap + kf * 512);
    }

    {   // slim prologue: 2 loads/row
        const int i = blockIdx.x * 256 + t;
        c40L[t]    = c40A[i];          // already -40*inter
        threshL[t] = threshA[i];
    }

    // stage B frags for j-tile jt into buffer buf: wave w loads frags 2w,2w+1
    auto stage = [&](int buf, int jt) {
        const unsigned short* src =
            Xf + ((size_t)(jt0 + jt) * 8 + wave * 2) * 512 + lane * 8;
        glds16(src,       &Bs[buf][wave * 2][0]);
        glds16(src + 512, &Bs[buf][wave * 2 + 1][0]);
    };

    stage(0, 0);
    __syncthreads();    // drains glds AND publishes c40L/threshL

    float accA[NT][4] = {};       // cnt
    float accB[NT][4] = {};       // nls
    float c40[NT][4], threshR[NT][4];
    int   icls[NT];
    #pragma unroll
    for (int tt = 0; tt < NT; ++tt) {
        icls[tt] = (i0 + tt * 16 + quad * 4) >> 3;
        int lbase = wave * 64 + tt * 16 + quad * 4;   // local row in block
        #pragma unroll
        for (int r = 0; r < 4; ++r) {
            c40[tt][r]     = c40L[lbase + r];
            threshR[tt][r] = threshL[lbase + r];
        }
    }

    int buf = 0;
    #pragma unroll 1
    for (int jt = 0; jt < 8; ++jt) {
        if (jt < 7) stage(buf ^ 1, jt + 1);

        bf16x8 bfr[8];
        #pragma unroll
        for (int kf = 0; kf < 8; ++kf)
            bfr[kf] = *reinterpret_cast<const bf16x8*>(&Bs[buf][kf][lane * 8]);

        f32x4 ac[NT];
        #pragma unroll
        for (int tt = 0; tt < NT; ++tt) ac[tt] = {0.f, 0.f, 0.f, 0.f};
        #pragma unroll
        for (int kf = 0; kf < 8; ++kf) {
            #pragma unroll
            for (int tt = 0; tt < NT; ++tt)
                ac[tt] = __builtin_amdgcn_mfma_f32_16x16x32_bf16(afrag[tt][kf], bfr[kf], ac[tt], 0, 0, 0);
        }

        const int jcls = (j0 + jt * 16 + n16) >> 3;
        #pragma unroll
        for (int tt = 0; tt < NT; ++tt) {
            const bool neg = (icls[tt] != jcls);
            #pragma unroll
            for (int r = 0; r < 4; ++r) {
                float s  = ac[tt][r];
                float sp = softplus_poly(fmaf(40.f, s, c40[tt][r]));
                float m  = (neg && s > threshR[tt][r]) ? 1.f : 0.f;
                accA[tt][r] += m;
                accB[tt][r] = fmaf(m, sp, accB[tt][r]);
            }
        }

        __syncthreads();    // drains glds for jt+1; frees buf for jt+2
        buf ^= 1;
    }

    // quad shuffle-reduce (16 lanes share rows) -> float4 partial stores
    #pragma unroll
    for (int tt = 0; tt < NT; ++tt) {
        #pragma unroll
        for (int r = 0; r < 4; ++r) {
            #pragma unroll
            for (int m = 8; m >= 1; m >>= 1) {
                accA[tt][r] += __shfl_xor(accA[tt][r], m);
                accB[tt][r] += __shfl_xor(accB[tt][r], m);
            }
        }
        if (n16 == 0) {
            int base = blockIdx.y * NROWS + i0 + tt * 16 + quad * 4;
            float4 va = {accA[tt][0], accA[tt][1], accA[tt][2], accA[tt][3]};
            float4 vb = {accB[tt][0], accB[tt][1], accB[tt][2], accB[tt][3]};
            *reinterpret_cast<float4*>(&cntPart[base]) = va;
            *reinterpret_cast<float4*>(&nlsPart[base]) = vb;
        }
    }
}

// 16 blocks x 256 threads; thread -> one row. Reduce cnt/nls partials ->
// rowLoss/rowInv, block-reduce 4 sums, last block combines -> out.
__global__ __launch_bounds__(256)
void finalAB_kernel(const float* __restrict__ cntPart,
                    const float* __restrict__ nlsPart,
                    const float* __restrict__ posLossA,
                    const float* __restrict__ rowPsum,
                    const float* __restrict__ rowNsum,
                    float* __restrict__ blkPart,      // 16*4 floats
                    unsigned int* __restrict__ counter,
                    float* __restrict__ out)
{
    const int t = threadIdx.x;
    const int i = blockIdx.x * 256 + t;

    float c = 0.f, n = 0.f;
    #pragma unroll
    for (int b = 0; b < NJB; ++b) {
        c += cntPart[b * NROWS + i];
        n += nlsPart[b * NROWS + i];
    }
    float loss = (c > 0.f) ? (posLossA[i] + 0.05f * n / c) : 0.f;
    float inv  = (c > 0.f) ? 0.f : 1.f;
    float pd   = rowPsum[i];
    float nd   = rowNsum[i];

    #pragma unroll
    for (int off = 32; off > 0; off >>= 1) {
        loss += __shfl_down(loss, off);
        inv  += __shfl_down(inv, off);
        pd   += __shfl_down(pd, off);
        nd   += __shfl_down(nd, off);
    }
    __shared__ float sl[4], si[4], sp[4], sq[4];
    int w = t >> 6;
    if ((t & 63) == 0) { sl[w] = loss; si[w] = inv; sp[w] = pd; sq[w] = nd; }
    __syncthreads();
    if (t == 0) {
        blkPart[blockIdx.x * 4 + 0] = sl[0] + sl[1] + sl[2] + sl[3];
        blkPart[blockIdx.x * 4 + 1] = si[0] + si[1] + si[2] + si[3];
        blkPart[blockIdx.x * 4 + 2] = sp[0] + sp[1] + sp[2] + sp[3];
        blkPart[blockIdx.x * 4 + 3] = sq[0] + sq[1] + sq[2] + sq[3];
        __threadfence();
        unsigned int old = atomicAdd(counter, 1u);
        sl[0] = (old == 15u) ? 1.f : 0.f;       // reuse LDS as flag
    }
    __syncthreads();
    if (sl[0] != 0.f && t < 64) {
        // last block: coherent read of all 64 partials (distinct addresses)
        float v = atomicAdd(&blkPart[t], 0.f);
        #pragma unroll
        for (int off = 4; off < 64; off <<= 1) v += __shfl_xor(v, off);
        // lanes 0..3 now hold totals: loss, inv, psum, nsum
        if (t == 0) out[0] = v / (float)NROWS;
        if (t == 1) out[1] = v / (float)NROWS;
        if (t == 2) out[2] = v / ((float)NROWS * (float)(KCLS - 1));
        if (t == 3) out[3] = v / ((float)NROWS * (float)(NROWS - KCLS));
    }
}

extern "C" void kernel_launch(void* const* d_in, const int* in_sizes, int n_in,
                              void* d_out, int out_size, void* d_ws, size_t ws_size,
                              hipStream_t stream)
{
    const float* X = (const float*)d_in[0];

    float* ws       = (float*)d_ws;
    float* cntPart  = ws;                                   // 32*4096
    float* nlsPart  = cntPart + NJB * NROWS;                // 32*4096
    float* sCol     = nlsPart + NJB * NROWS;                // 256
    float* c40A     = sCol + 256;                           // 4096
    float* threshA  = c40A + NROWS;                         // 4096
    float* posLossA = threshA + NROWS;                      // 4096
    float* rowPsum  = posLossA + NROWS;                     // 4096
    float* rowNsum  = rowPsum + NROWS;                      // 4096
    float* blkPart  = rowNsum + NROWS;                      // 64
    unsigned int* counter = (unsigned int*)(blkPart + 64);  // 1 (+pad)
    unsigned short* Gfhi = (unsigned short*)(counter + 16); // 128 KB
    unsigned short* Gflo = Gfhi + 65536;                    // 128 KB
    unsigned short* Xf   = Gflo + 65536;                    // 2 MB
    // total ws use: ~3.4 MB; counter+sCol zeroed by convert

    convert_kernel<<<512, 256, 0, stream>>>(X, Xf, counter, sCol);

    gram_kernel<<<dim3(8, 8), 256, 0, stream>>>(X, Gfhi, Gflo, sCol);

    rowstats_kernel<<<64, 256, 0, stream>>>(X, Xf, Gfhi, Gflo, sCol,
                                            c40A, threshA, posLossA,
                                            rowPsum, rowNsum);

    loss_gemm_kernel<<<dim3(16, 32), 256, 0, stream>>>(Xf, c40A, threshA,
                                                       cntPart, nlsPart);

    finalAB_kernel<<<16, 256, 0, stream>>>(cntPart, nlsPart, posLossA,
                                           rowPsum, rowNsum, blkPart, counter,
                                           (float*)d_out);
}

// Round 3
// 106.357 us; speedup vs baseline: 1.2995x; 1.2995x over previous
//
#include <hip/hip_runtime.h>
#include <math.h>

// MarginDevianceLoss: N=4096, D=256, K=8, targets = i/8.
// Outputs: [loss, prec, pos_d, neg_d] fp32.
//
// R18: R17's Gram factorization was correct (absmax unchanged) but gram+
// rowstats ran at 64 blocks = 25% of CUs at 1 wave/SIMD -> latency-exposed
// (~50-80us pair). Fix is occupancy, not math:
//   - gram: grid (8,8,4), z splits K into 1024-row chunks; partials combined
//     via fp32 atomicAdd into gPart kept in FRAG-MAJOR layout (same f/slot/e
//     index math as R17's verified epilogue). 256 blocks, 256 scalar
//     loads/thread (was 1024).
//   - rowstats: 256 blocks (1 i-tile each), 4 waves split the jt loop 4-way;
//     gPart read as fp32 vectors, hi/lo bf16 split done in registers with
//     the identical RNE arithmetic.
// Everything else (convert, loss_gemm, finalAB) is R16/R17-verified verbatim.
// Dispatches: convert -> gram -> rowstats -> lossGemm -> finalAB.
// Kept lessons: frag-major bf16 Xf + glds B-staging (R11); no inline fp32
// staging (R12); no big atomic fan-in / grid barriers (R7/R13); small kernels
// need full-machine grids (R17).

#define NROWS 4096
#define DIM   256
#define KCLS  8
#define NJB   32     // j-blocks = partials per row (loss gemm)
#define NT    4      // i-tiles per wave (loss gemm)

typedef __bf16 bf16x8 __attribute__((ext_vector_type(8)));
typedef float  f32x4  __attribute__((ext_vector_type(4)));

// log(1+exp(z)) = max(z,0) + ln2 * log2(1 + exp2(-|z|*log2e));
// log2(1+u), u in (0,1], quartic fit (abs err <= ~4e-4).
__device__ __forceinline__ float softplus_poly(float z) {
    float u = __builtin_exp2f(-1.4426950408889634f * __builtin_fabsf(z));
    float p = u * (1.4426950f + u * (-0.6949650f + u * (0.3454302f + u * -0.0931600f)));
    return fmaf(p, 0.6931471805599453f, fmaxf(z, 0.f));
}

__device__ __forceinline__ unsigned int pack_bf2(float a, float b) {
    unsigned int ua = __float_as_uint(a);
    unsigned int ub = __float_as_uint(b);
    ua = (ua + 0x7FFFu + ((ua >> 16) & 1u)) >> 16;   // RNE
    ub = (ub + 0x7FFFu + ((ub >> 16) & 1u)) >> 16;
    return ua | (ub << 16);
}

// fp32 v -> (hi bf16, lo bf16) with hi = RNE(v), lo = RNE(v - hi); packs two
// elements into one halfword-pair each. Matches R17's gram epilogue split.
__device__ __forceinline__ void split_pair(float a, float b,
                                           unsigned int& hw, unsigned int& lw) {
    unsigned int ua = __float_as_uint(a), ub = __float_as_uint(b);
    unsigned int ha = (ua + 0x7FFFu + ((ua >> 16) & 1u)) & 0xFFFF0000u;
    unsigned int hb = (ub + 0x7FFFu + ((ub >> 16) & 1u)) & 0xFFFF0000u;
    hw = (ha >> 16) | hb;
    lw = pack_bf2(a - __uint_as_float(ha), b - __uint_as_float(hb));
}

__device__ __forceinline__ void glds16(const unsigned short* g, unsigned short* l) {
    // HW: each lane reads 16 B at its own g; LDS dest = uniform l + lane*16.
    __builtin_amdgcn_global_load_lds(
        (const __attribute__((address_space(1))) void*)g,
        (__attribute__((address_space(3))) void*)l, 16, 0, 0);
}

// X (fp32 row-major) -> Xf (bf16 fragment-major):
// Xf[((tile*8 + kf)*64 + lane)*8 + e] = X[tile*16 + (lane&15)][kf*32 + (lane>>4)*8 + e]
// Also zeroes sCol (gram), gPart (gram atomics) and the finalAB done-counter.
__global__ __launch_bounds__(256)
void convert_kernel(const float* __restrict__ X, unsigned short* __restrict__ Xf,
                    unsigned int* __restrict__ counter, float* __restrict__ sCol,
                    float* __restrict__ gPart)
{
    int v = blockIdx.x * 256 + threadIdx.x;    // 131072 fragment-slices of 16 B
    if (v == 0) *counter = 0u;
    if (v < 256) sCol[v] = 0.f;
    if (v < 65536) gPart[v] = 0.f;
    int tile = v >> 9;
    int kf   = (v >> 6) & 7;
    int lane = v & 63;
    int row  = tile * 16 + (lane & 15);
    int c4   = kf * 8 + (lane >> 4) * 2;       // col/4
    const float4* X4 = reinterpret_cast<const float4*>(X);
    float4 a = X4[row * 64 + c4];
    float4 b = X4[row * 64 + c4 + 1];
    uint4 o;
    o.x = pack_bf2(a.x, a.y);
    o.y = pack_bf2(a.z, a.w);
    o.z = pack_bf2(b.x, b.y);
    o.w = pack_bf2(b.z, b.w);
    reinterpret_cast<uint4*>(Xf)[v] = o;
}

// G = Xb^T Xb (256x256, fp32 accum via MFMA), accumulated via fp32 atomicAdd
// into gPart stored FRAG-MAJOR:
//   gPart[(f*64 + slot)*8 + e], f = jt*8 + kf, holding
//   G[kf*32 + (slot>>4)*8 + e][jt*16 + (slot&15)]
// Grid (8,8,4): block = 32x32 G region x 1024-row K-chunk (z); 4 waves split
// the chunk in quarters, LDS-reduce, then each of 256 threads owns one
// (tile,cell) -> 4 atomicAdds. blockIdx.y==0 blocks accumulate colsum s.
__global__ __launch_bounds__(256)
void gram_kernel(const float* __restrict__ X,
                 float* __restrict__ gPart,
                 float* __restrict__ sCol)
{
    __shared__ float red[4][4][64][4];         // 16 KB
    const int t    = threadIdx.x;
    const int lane = t & 63;
    const int w    = t >> 6;
    const int q    = lane >> 4;
    const int n    = lane & 15;
    const int c0   = blockIdx.x * 32;
    const int d0   = blockIdx.y * 32;

    f32x4 ac[2][2];
    #pragma unroll
    for (int ct = 0; ct < 2; ++ct)
        #pragma unroll
        for (int dt = 0; dt < 2; ++dt)
            ac[ct][dt] = {0.f, 0.f, 0.f, 0.f};
    float sacc0 = 0.f, sacc1 = 0.f;

    // rows: z*1024 + w*256 + ks*32 + q*8 + e  (bijective over [0,4096))
    const float* base = X + (blockIdx.z * 1024 + w * 256 + q * 8) * 256;
    for (int ks = 0; ks < 8; ++ks) {
        bf16x8 af[2], bfr[2];
        #pragma unroll
        for (int ct = 0; ct < 2; ++ct) {
            float v[8];
            #pragma unroll
            for (int e = 0; e < 8; ++e) v[e] = base[e * 256 + c0 + ct * 16 + n];
            if (blockIdx.y == 0) {
                float sv = ((v[0]+v[1])+(v[2]+v[3])) + ((v[4]+v[5])+(v[6]+v[7]));
                if (ct == 0) sacc0 += sv; else sacc1 += sv;
            }
            uint4 u;
            u.x = pack_bf2(v[0], v[1]); u.y = pack_bf2(v[2], v[3]);
            u.z = pack_bf2(v[4], v[5]); u.w = pack_bf2(v[6], v[7]);
            af[ct] = *reinterpret_cast<bf16x8*>(&u);
        }
        #pragma unroll
        for (int dt = 0; dt < 2; ++dt) {
            float v[8];
            #pragma unroll
            for (int e = 0; e < 8; ++e) v[e] = base[e * 256 + d0 + dt * 16 + n];
            uint4 u;
            u.x = pack_bf2(v[0], v[1]); u.y = pack_bf2(v[2], v[3]);
            u.z = pack_bf2(v[4], v[5]); u.w = pack_bf2(v[6], v[7]);
            bfr[dt] = *reinterpret_cast<bf16x8*>(&u);
        }
        #pragma unroll
        for (int ct = 0; ct < 2; ++ct)
            #pragma unroll
            for (int dt = 0; dt < 2; ++dt)
                ac[ct][dt] = __builtin_amdgcn_mfma_f32_16x16x32_bf16(af[ct], bfr[dt], ac[ct][dt], 0, 0, 0);
        base += 32 * 256;
    }

    if (blockIdx.y == 0) {
        sacc0 += __shfl_xor(sacc0, 16); sacc0 += __shfl_xor(sacc0, 32);
        sacc1 += __shfl_xor(sacc1, 16); sacc1 += __shfl_xor(sacc1, 32);
        if (lane < 16) {
            atomicAdd(&sCol[c0 + lane], sacc0);
            atomicAdd(&sCol[c0 + 16 + lane], sacc1);
        }
    }

    #pragma unroll
    for (int ct = 0; ct < 2; ++ct)
        #pragma unroll
        for (int dt = 0; dt < 2; ++dt)
            *reinterpret_cast<f32x4*>(&red[w][ct * 2 + dt][lane][0]) = ac[ct][dt];
    __syncthreads();

    const int tile = t >> 6;                   // re-partition: thread -> (tile, cell)
    const int ln   = t & 63;
    float v[4];
    #pragma unroll
    for (int r = 0; r < 4; ++r)
        v[r] = (red[0][tile][ln][r] + red[1][tile][ln][r])
             + (red[2][tile][ln][r] + red[3][tile][ln][r]);
    const int ct = tile >> 1, dt = tile & 1;
    const int qq = ln >> 4,  nn = ln & 15;
    // C-layout cell: G[c][d], c = c0+ct*16+qq*4+r, d = d0+dt*16+nn.
    // Frag dest: f = jt*8+kf = (by*2+dt)*8 + bx; slot = (ct*2+(qq>>1))*16+nn;
    // e = (qq&1)*4 + r.  (verified index math from R17)
    const int f    = (blockIdx.y * 2 + dt) * 8 + blockIdx.x;
    const int slot = (ct * 2 + (qq >> 1)) * 16 + nn;
    const int idx  = (f * 64 + slot) * 8 + (qq & 1) * 4;   // float index
    #pragma unroll
    for (int r = 0; r < 4; ++r)
        atomicAdd(&gPart[idx + r], v[r]);
}

// Per-row stats WITHOUT the NxN GEMM. Grid 256 x 256 thr: block = ONE i-tile
// (16 rows); 4 waves split the jt loop 4-way (full-machine occupancy — R17's
// 64-block version was latency-bound at 1 wave/SIMD on 25% of CUs).
// classSim = mfma(afrag, afrag) diag blocks (wave 0); Y = Xb@(Ghi+Glo) with
// G read from fp32 gPart and hi/lo-split in registers (same RNE arithmetic
// as R17); SQ_i = sum_d Y[i][d]*x[i][d], S_i = sum_d s[d]*x[i][d].
// Then 1 thread/row (t<16) computes inter/thresh/posLoss/psum/nsum.
__global__ __launch_bounds__(256)
void rowstats_kernel(const float* __restrict__ X,
                     const unsigned short* __restrict__ Xf,
                     const float* __restrict__ gPart,
                     const float* __restrict__ sCol,
                     float* __restrict__ c40A, float* __restrict__ threshA,
                     float* __restrict__ posLossA,
                     float* __restrict__ rowPsum, float* __restrict__ rowNsum)
{
    __shared__ float csL[16][8];
    __shared__ float sqL[4][16], smL[4][16];
    const int t    = threadIdx.x;
    const int lane = t & 63;
    const int w    = t >> 6;
    const int q    = lane >> 4;
    const int n    = lane & 15;
    const int it   = blockIdx.x;
    const int i0   = it * 16;

    bf16x8 afrag[8];
    const unsigned short* ap = Xf + (size_t)it * 8 * 512 + lane * 8;
    #pragma unroll
    for (int kf = 0; kf < 8; ++kf)
        afrag[kf] = *reinterpret_cast<const bf16x8*>(ap + kf * 512);

    // classSim: self-tile sim (afrag works as both A and B fragment)
    if (w == 0) {
        f32x4 cac = {0.f, 0.f, 0.f, 0.f};
        #pragma unroll
        for (int kf = 0; kf < 8; ++kf)
            cac = __builtin_amdgcn_mfma_f32_16x16x32_bf16(afrag[kf], afrag[kf], cac, 0, 0, 0);
        #pragma unroll
        for (int r = 0; r < 4; ++r) {
            int row = q * 4 + r;
            if (((row ^ n) >> 3) == 0) csL[row][n & 7] = cac[r];
        }
    }

    float sqa[4] = {0.f, 0.f, 0.f, 0.f};
    float sma[4] = {0.f, 0.f, 0.f, 0.f};
    #pragma unroll 1
    for (int jt = w * 4; jt < w * 4 + 4; ++jt) {
        const float* gp = gPart + (size_t)jt * 8 * 512 + lane * 8;
        f32x4 y0 = {0.f, 0.f, 0.f, 0.f};
        f32x4 y1 = {0.f, 0.f, 0.f, 0.f};
        #pragma unroll
        for (int kf = 0; kf < 8; ++kf) {
            float4 ga = *reinterpret_cast<const float4*>(gp + kf * 512);
            float4 gb = *reinterpret_cast<const float4*>(gp + kf * 512 + 4);
            uint4 H, L;
            split_pair(ga.x, ga.y, H.x, L.x);
            split_pair(ga.z, ga.w, H.y, L.y);
            split_pair(gb.x, gb.y, H.z, L.z);
            split_pair(gb.z, gb.w, H.w, L.w);
            bf16x8 gh = *reinterpret_cast<bf16x8*>(&H);
            bf16x8 gl = *reinterpret_cast<bf16x8*>(&L);
            y0 = __builtin_amdgcn_mfma_f32_16x16x32_bf16(afrag[kf], gh, y0, 0, 0, 0);
            y1 = __builtin_amdgcn_mfma_f32_16x16x32_bf16(afrag[kf], gl, y1, 0, 0, 0);
        }
        int d = jt * 16 + n;
        float sd = sCol[d];
        #pragma unroll
        for (int r = 0; r < 4; ++r) {
            float xl = X[(i0 + q * 4 + r) * 256 + d];
            sqa[r] = fmaf(y0[r] + y1[r], xl, sqa[r]);
            sma[r] = fmaf(sd, xl, sma[r]);
        }
    }
    #pragma unroll
    for (int r = 0; r < 4; ++r) {
        float a = sqa[r], b = sma[r];
        #pragma unroll
        for (int m = 8; m >= 1; m >>= 1) {
            a += __shfl_xor(a, m);
            b += __shfl_xor(b, m);
        }
        if (n == 0) { sqL[w][q * 4 + r] = a; smL[w][q * 4 + r] = b; }
    }
    __syncthreads();

    if (t < 16) {
        const int i = i0 + t;
        const int self = i & 7;
        float cs[KCLS];
        #pragma unroll
        for (int m = 0; m < KCLS; ++m) cs[m] = csL[t][m];
        float sii = cs[self];
        float psum = 0.f, psq = 0.f, pmin = 1e30f;
        #pragma unroll
        for (int m = 0; m < KCLS; ++m) {
            if (m != self) {
                psum += cs[m];
                psq  += cs[m] * cs[m];
                pmin  = fminf(pmin, cs[m]);
            }
        }
        const float p = (float)(KCLS - 1);            // 7
        const float mneg = (float)(NROWS - KCLS);     // 4088
        float S  = (smL[0][t] + smL[1][t]) + (smL[2][t] + smL[3][t]);
        float SQ = (sqL[0][t] + sqL[1][t]) + (sqL[2][t] + sqL[3][t]);
        float nsum = S - psum - sii;
        float nsq  = SQ - psq - sii * sii;
        float pmean = psum / p;
        float pstd  = sqrtf(fmaxf(psq / p - pmean * pmean, 0.f));
        float nmean = nsum / mneg;
        float nstd  = sqrtf(fmaxf(nsq / mneg - nmean * nmean, 0.f));
        float inter = 0.8f * (nstd * pmean + pstd * nmean) / (pstd + nstd) + 0.1f;
        float pl = 0.f;
        #pragma unroll
        for (int m = 0; m < KCLS; ++m) {
            if (m != self) pl += softplus_poly(-10.f * (cs[m] - inter));
        }
        c40A[i]     = -40.f * inter;
        threshA[i]  = pmin - 0.05f;
        posLossA[i] = pl * (0.2f / p);
        rowPsum[i]  = psum;
        rowNsum[i]  = nsum;
    }
}

// Loss GEMM (R16 loop verbatim). Grid (16,32). Block: 4 waves; wave w ->
// i-tiles [bx*16+w*4, +4) (64 rows, A cached in regs). All waves sweep
// j-tiles [by*8,+8); B staged via LDS (global_load_lds, double-buffered).
// Prologue just loads precomputed -40*inter / thresh per row.
__global__ __launch_bounds__(256)
void loss_gemm_kernel(const unsigned short* __restrict__ Xf,
                      const float* __restrict__ c40A,
                      const float* __restrict__ threshA,
                      float* __restrict__ cntPart,
                      float* __restrict__ nlsPart)
{
    __shared__ __align__(16) unsigned short Bs[2][8][512];   // 2 x 8 KB
    __shared__ float c40L[256], threshL[256];

    const int t    = threadIdx.x;
    const int lane = t & 63;
    const int wave = t >> 6;
    const int quad = lane >> 4;
    const int n16  = lane & 15;
    const int it0  = blockIdx.x * 16 + wave * NT;
    const int i0   = it0 * 16;
    const int j0   = blockIdx.y * 128;
    const int jt0  = blockIdx.y * 8;

    // A fragments: NT i-tiles x 8 k-frags, coalesced 1-KB global loads
    bf16x8 afrag[NT][8];
    #pragma unroll
    for (int tt = 0; tt < NT; ++tt) {
        const unsigned short* ap = Xf + ((size_t)(it0 + tt) * 8) * 512 + lane * 8;
        #pragma unroll
        for (int kf = 0; kf < 8; ++kf)
            afrag[tt][kf] = *reinterpret_cast<const bf16x8*>(ap + kf * 512);
    }

    {   // slim prologue: 2 loads/row
        const int i = blockIdx.x * 256 + t;
        c40L[t]    = c40A[i];          // already -40*inter
        threshL[t] = threshA[i];
    }

    // stage B frags for j-tile jt into buffer buf: wave w loads frags 2w,2w+1
    auto stage = [&](int buf, int jt) {
        const unsigned short* src =
            Xf + ((size_t)(jt0 + jt) * 8 + wave * 2) * 512 + lane * 8;
        glds16(src,       &Bs[buf][wave * 2][0]);
        glds16(src + 512, &Bs[buf][wave * 2 + 1][0]);
    };

    stage(0, 0);
    __syncthreads();    // drains glds AND publishes c40L/threshL

    float accA[NT][4] = {};       // cnt
    float accB[NT][4] = {};       // nls
    float c40[NT][4], threshR[NT][4];
    int   icls[NT];
    #pragma unroll
    for (int tt = 0; tt < NT; ++tt) {
        icls[tt] = (i0 + tt * 16 + quad * 4) >> 3;
        int lbase = wave * 64 + tt * 16 + quad * 4;   // local row in block
        #pragma unroll
        for (int r = 0; r < 4; ++r) {
            c40[tt][r]     = c40L[lbase + r];
            threshR[tt][r] = threshL[lbase + r];
        }
    }

    int buf = 0;
    #pragma unroll 1
    for (int jt = 0; jt < 8; ++jt) {
        if (jt < 7) stage(buf ^ 1, jt + 1);

        bf16x8 bfr[8];
        #pragma unroll
        for (int kf = 0; kf < 8; ++kf)
            bfr[kf] = *reinterpret_cast<const bf16x8*>(&Bs[buf][kf][lane * 8]);

        f32x4 ac[NT];
        #pragma unroll
        for (int tt = 0; tt < NT; ++tt) ac[tt] = {0.f, 0.f, 0.f, 0.f};
        #pragma unroll
        for (int kf = 0; kf < 8; ++kf) {
            #pragma unroll
            for (int tt = 0; tt < NT; ++tt)
                ac[tt] = __builtin_amdgcn_mfma_f32_16x16x32_bf16(afrag[tt][kf], bfr[kf], ac[tt], 0, 0, 0);
        }

        const int jcls = (j0 + jt * 16 + n16) >> 3;
        #pragma unroll
        for (int tt = 0; tt < NT; ++tt) {
            const bool neg = (icls[tt] != jcls);
            #pragma unroll
            for (int r = 0; r < 4; ++r) {
                float s  = ac[tt][r];
                float sp = softplus_poly(fmaf(40.f, s, c40[tt][r]));
                float m  = (neg && s > threshR[tt][r]) ? 1.f : 0.f;
                accA[tt][r] += m;
                accB[tt][r] = fmaf(m, sp, accB[tt][r]);
            }
        }

        __syncthreads();    // drains glds for jt+1; frees buf for jt+2
        buf ^= 1;
    }

    // quad shuffle-reduce (16 lanes share rows) -> float4 partial stores
    #pragma unroll
    for (int tt = 0; tt < NT; ++tt) {
        #pragma unroll
        for (int r = 0; r < 4; ++r) {
            #pragma unroll
            for (int m = 8; m >= 1; m >>= 1) {
                accA[tt][r] += __shfl_xor(accA[tt][r], m);
                accB[tt][r] += __shfl_xor(accB[tt][r], m);
            }
        }
        if (n16 == 0) {
            int base = blockIdx.y * NROWS + i0 + tt * 16 + quad * 4;
            float4 va = {accA[tt][0], accA[tt][1], accA[tt][2], accA[tt][3]};
            float4 vb = {accB[tt][0], accB[tt][1], accB[tt][2], accB[tt][3]};
            *reinterpret_cast<float4*>(&cntPart[base]) = va;
            *reinterpret_cast<float4*>(&nlsPart[base]) = vb;
        }
    }
}

// 16 blocks x 256 threads; thread -> one row. Reduce cnt/nls partials ->
// rowLoss/rowInv, block-reduce 4 sums, last block combines -> out.
__global__ __launch_bounds__(256)
void finalAB_kernel(const float* __restrict__ cntPart,
                    const float* __restrict__ nlsPart,
                    const float* __restrict__ posLossA,
                    const float* __restrict__ rowPsum,
                    const float* __restrict__ rowNsum,
                    float* __restrict__ blkPart,      // 16*4 floats
                    unsigned int* __restrict__ counter,
                    float* __restrict__ out)
{
    const int t = threadIdx.x;
    const int i = blockIdx.x * 256 + t;

    float c = 0.f, n = 0.f;
    #pragma unroll
    for (int b = 0; b < NJB; ++b) {
        c += cntPart[b * NROWS + i];
        n += nlsPart[b * NROWS + i];
    }
    float loss = (c > 0.f) ? (posLossA[i] + 0.05f * n / c) : 0.f;
    float inv  = (c > 0.f) ? 0.f : 1.f;
    float pd   = rowPsum[i];
    float nd   = rowNsum[i];

    #pragma unroll
    for (int off = 32; off > 0; off >>= 1) {
        loss += __shfl_down(loss, off);
        inv  += __shfl_down(inv, off);
        pd   += __shfl_down(pd, off);
        nd   += __shfl_down(nd, off);
    }
    __shared__ float sl[4], si[4], sp[4], sq[4];
    int w = t >> 6;
    if ((t & 63) == 0) { sl[w] = loss; si[w] = inv; sp[w] = pd; sq[w] = nd; }
    __syncthreads();
    if (t == 0) {
        blkPart[blockIdx.x * 4 + 0] = sl[0] + sl[1] + sl[2] + sl[3];
        blkPart[blockIdx.x * 4 + 1] = si[0] + si[1] + si[2] + si[3];
        blkPart[blockIdx.x * 4 + 2] = sp[0] + sp[1] + sp[2] + sp[3];
        blkPart[blockIdx.x * 4 + 3] = sq[0] + sq[1] + sq[2] + sq[3];
        __threadfence();
        unsigned int old = atomicAdd(counter, 1u);
        sl[0] = (old == 15u) ? 1.f : 0.f;       // reuse LDS as flag
    }
    __syncthreads();
    if (sl[0] != 0.f && t < 64) {
        // last block: coherent read of all 64 partials (distinct addresses)
        float v = atomicAdd(&blkPart[t], 0.f);
        #pragma unroll
        for (int off = 4; off < 64; off <<= 1) v += __shfl_xor(v, off);
        // lanes 0..3 now hold totals: loss, inv, psum, nsum
        if (t == 0) out[0] = v / (float)NROWS;
        if (t == 1) out[1] = v / (float)NROWS;
        if (t == 2) out[2] = v / ((float)NROWS * (float)(KCLS - 1));
        if (t == 3) out[3] = v / ((float)NROWS * (float)(NROWS - KCLS));
    }
}

extern "C" void kernel_launch(void* const* d_in, const int* in_sizes, int n_in,
                              void* d_out, int out_size, void* d_ws, size_t ws_size,
                              hipStream_t stream)
{
    const float* X = (const float*)d_in[0];

    float* ws       = (float*)d_ws;
    float* cntPart  = ws;                                   // 32*4096
    float* nlsPart  = cntPart + NJB * NROWS;                // 32*4096
    float* sCol     = nlsPart + NJB * NROWS;                // 256
    float* c40A     = sCol + 256;                           // 4096
    float* threshA  = c40A + NROWS;                         // 4096
    float* posLossA = threshA + NROWS;                      // 4096
    float* rowPsum  = posLossA + NROWS;                     // 4096
    float* rowNsum  = rowPsum + NROWS;                      // 4096
    float* blkPart  = rowNsum + NROWS;                      // 64
    unsigned int* counter = (unsigned int*)(blkPart + 64);  // 1 (+pad)
    float* gPart    = (float*)(counter + 16);               // 65536 (256 KB)
    unsigned short* Xf = (unsigned short*)(gPart + 65536);  // 2 MB
    // total ws use: ~3.4 MB; counter+sCol+gPart zeroed by convert

    convert_kernel<<<512, 256, 0, stream>>>(X, Xf, counter, sCol, gPart);

    gram_kernel<<<dim3(8, 8, 4), 256, 0, stream>>>(X, gPart, sCol);

    rowstats_kernel<<<256, 256, 0, stream>>>(X, Xf, gPart, sCol,
                                             c40A, threshA, posLossA,
                                             rowPsum, rowNsum);

    loss_gemm_kernel<<<dim3(16, 32), 256, 0, stream>>>(Xf, c40A, threshA,
                                                       cntPart, nlsPart);

    finalAB_kernel<<<16, 256, 0, stream>>>(cntPart, nlsPart, posLossA,
                                           rowPsum, rowNsum, blkPart, counter,
                                           (float*)d_out);
}

// Round 4
// 106.102 us; speedup vs baseline: 1.3027x; 1.0024x over previous
//
#include <hip/hip_runtime.h>
#include <math.h>

// MarginDevianceLoss: N=4096, D=256, K=8, targets = i/8.
// Outputs: [loss, prec, pos_d, neg_d] fp32.
//
// R19: R18's occupancy fix recovered 32us but gram+rowstats still ran at
// 1 wave/SIMD (zero TLP). Two pure occupancy levers, no math changes:
//   - gram: grid (8,8,8) = 512 blocks (2/CU, 2 waves/SIMD), 128 loads/thread,
//     ks loop fully unrolled for load ILP. Partials via fp32 atomicAdd into
//     frag-major gPart (R17-verified f/slot/e index math).
//   - rowstats: 256 blocks x 512 threads (8 waves, 2 waves/SIMD); wave w
//     handles jt = 2w,2w+1 (unrolled pair -> both iterations' G loads in
//     flight). gPart read fp32, hi/lo bf16 split in regs (R17 RNE arith).
// convert / loss_gemm / finalAB are R16/R18-verified verbatim.
// Dispatches: convert -> gram -> rowstats -> lossGemm -> finalAB.
// Kept lessons: frag-major bf16 Xf + glds B-staging (R11); no inline fp32
// staging (R12); no big atomic fan-in / grid barriers (R7/R13); small
// kernels need full-machine grids AND >=2 waves/SIMD (R17/R18).

#define NROWS 4096
#define DIM   256
#define KCLS  8
#define NJB   32     // j-blocks = partials per row (loss gemm)
#define NT    4      // i-tiles per wave (loss gemm)

typedef __bf16 bf16x8 __attribute__((ext_vector_type(8)));
typedef float  f32x4  __attribute__((ext_vector_type(4)));

// log(1+exp(z)) = max(z,0) + ln2 * log2(1 + exp2(-|z|*log2e));
// log2(1+u), u in (0,1], quartic fit (abs err <= ~4e-4).
__device__ __forceinline__ float softplus_poly(float z) {
    float u = __builtin_exp2f(-1.4426950408889634f * __builtin_fabsf(z));
    float p = u * (1.4426950f + u * (-0.6949650f + u * (0.3454302f + u * -0.0931600f)));
    return fmaf(p, 0.6931471805599453f, fmaxf(z, 0.f));
}

__device__ __forceinline__ unsigned int pack_bf2(float a, float b) {
    unsigned int ua = __float_as_uint(a);
    unsigned int ub = __float_as_uint(b);
    ua = (ua + 0x7FFFu + ((ua >> 16) & 1u)) >> 16;   // RNE
    ub = (ub + 0x7FFFu + ((ub >> 16) & 1u)) >> 16;
    return ua | (ub << 16);
}

// fp32 v -> (hi bf16, lo bf16) with hi = RNE(v), lo = RNE(v - hi); packs two
// elements into one halfword-pair each. Matches R17's gram epilogue split.
__device__ __forceinline__ void split_pair(float a, float b,
                                           unsigned int& hw, unsigned int& lw) {
    unsigned int ua = __float_as_uint(a), ub = __float_as_uint(b);
    unsigned int ha = (ua + 0x7FFFu + ((ua >> 16) & 1u)) & 0xFFFF0000u;
    unsigned int hb = (ub + 0x7FFFu + ((ub >> 16) & 1u)) & 0xFFFF0000u;
    hw = (ha >> 16) | hb;
    lw = pack_bf2(a - __uint_as_float(ha), b - __uint_as_float(hb));
}

__device__ __forceinline__ void glds16(const unsigned short* g, unsigned short* l) {
    // HW: each lane reads 16 B at its own g; LDS dest = uniform l + lane*16.
    __builtin_amdgcn_global_load_lds(
        (const __attribute__((address_space(1))) void*)g,
        (__attribute__((address_space(3))) void*)l, 16, 0, 0);
}

// X (fp32 row-major) -> Xf (bf16 fragment-major):
// Xf[((tile*8 + kf)*64 + lane)*8 + e] = X[tile*16 + (lane&15)][kf*32 + (lane>>4)*8 + e]
// Also zeroes sCol (gram), gPart (gram atomics) and the finalAB done-counter.
__global__ __launch_bounds__(256)
void convert_kernel(const float* __restrict__ X, unsigned short* __restrict__ Xf,
                    unsigned int* __restrict__ counter, float* __restrict__ sCol,
                    float* __restrict__ gPart)
{
    int v = blockIdx.x * 256 + threadIdx.x;    // 131072 fragment-slices of 16 B
    if (v == 0) *counter = 0u;
    if (v < 256) sCol[v] = 0.f;
    if (v < 65536) gPart[v] = 0.f;
    int tile = v >> 9;
    int kf   = (v >> 6) & 7;
    int lane = v & 63;
    int row  = tile * 16 + (lane & 15);
    int c4   = kf * 8 + (lane >> 4) * 2;       // col/4
    const float4* X4 = reinterpret_cast<const float4*>(X);
    float4 a = X4[row * 64 + c4];
    float4 b = X4[row * 64 + c4 + 1];
    uint4 o;
    o.x = pack_bf2(a.x, a.y);
    o.y = pack_bf2(a.z, a.w);
    o.z = pack_bf2(b.x, b.y);
    o.w = pack_bf2(b.z, b.w);
    reinterpret_cast<uint4*>(Xf)[v] = o;
}

// G = Xb^T Xb (256x256, fp32 accum via MFMA), accumulated via fp32 atomicAdd
// into gPart stored FRAG-MAJOR:
//   gPart[(f*64 + slot)*8 + e], f = jt*8 + kf, holding
//   G[kf*32 + (slot>>4)*8 + e][jt*16 + (slot&15)]
// Grid (8,8,8): block = 32x32 G region x 512-row K-chunk (z); 4 waves split
// the chunk in quarters (128 rows each, ks x 32), LDS-reduce, then each of
// 256 threads owns one (tile,cell) -> 4 atomicAdds. blockIdx.y==0 blocks
// also accumulate colsum s.
__global__ __launch_bounds__(256)
void gram_kernel(const float* __restrict__ X,
                 float* __restrict__ gPart,
                 float* __restrict__ sCol)
{
    __shared__ float red[4][4][64][4];         // 16 KB
    const int t    = threadIdx.x;
    const int lane = t & 63;
    const int w    = t >> 6;
    const int q    = lane >> 4;
    const int n    = lane & 15;
    const int c0   = blockIdx.x * 32;
    const int d0   = blockIdx.y * 32;

    f32x4 ac[2][2];
    #pragma unroll
    for (int ct = 0; ct < 2; ++ct)
        #pragma unroll
        for (int dt = 0; dt < 2; ++dt)
            ac[ct][dt] = {0.f, 0.f, 0.f, 0.f};
    float sacc0 = 0.f, sacc1 = 0.f;

    // rows: z*512 + w*128 + ks*32 + q*8 + e  (bijective over [0,4096))
    const float* base = X + (blockIdx.z * 512 + w * 128 + q * 8) * 256;
    #pragma unroll
    for (int ks = 0; ks < 4; ++ks) {
        bf16x8 af[2], bfr[2];
        #pragma unroll
        for (int ct = 0; ct < 2; ++ct) {
            float v[8];
            #pragma unroll
            for (int e = 0; e < 8; ++e) v[e] = base[e * 256 + c0 + ct * 16 + n];
            if (blockIdx.y == 0) {
                float sv = ((v[0]+v[1])+(v[2]+v[3])) + ((v[4]+v[5])+(v[6]+v[7]));
                if (ct == 0) sacc0 += sv; else sacc1 += sv;
            }
            uint4 u;
            u.x = pack_bf2(v[0], v[1]); u.y = pack_bf2(v[2], v[3]);
            u.z = pack_bf2(v[4], v[5]); u.w = pack_bf2(v[6], v[7]);
            af[ct] = *reinterpret_cast<bf16x8*>(&u);
        }
        #pragma unroll
        for (int dt = 0; dt < 2; ++dt) {
            float v[8];
            #pragma unroll
            for (int e = 0; e < 8; ++e) v[e] = base[e * 256 + d0 + dt * 16 + n];
            uint4 u;
            u.x = pack_bf2(v[0], v[1]); u.y = pack_bf2(v[2], v[3]);
            u.z = pack_bf2(v[4], v[5]); u.w = pack_bf2(v[6], v[7]);
            bfr[dt] = *reinterpret_cast<bf16x8*>(&u);
        }
        #pragma unroll
        for (int ct = 0; ct < 2; ++ct)
            #pragma unroll
            for (int dt = 0; dt < 2; ++dt)
                ac[ct][dt] = __builtin_amdgcn_mfma_f32_16x16x32_bf16(af[ct], bfr[dt], ac[ct][dt], 0, 0, 0);
        base += 32 * 256;
    }

    if (blockIdx.y == 0) {
        sacc0 += __shfl_xor(sacc0, 16); sacc0 += __shfl_xor(sacc0, 32);
        sacc1 += __shfl_xor(sacc1, 16); sacc1 += __shfl_xor(sacc1, 32);
        if (lane < 16) {
            atomicAdd(&sCol[c0 + lane], sacc0);
            atomicAdd(&sCol[c0 + 16 + lane], sacc1);
        }
    }

    #pragma unroll
    for (int ct = 0; ct < 2; ++ct)
        #pragma unroll
        for (int dt = 0; dt < 2; ++dt)
            *reinterpret_cast<f32x4*>(&red[w][ct * 2 + dt][lane][0]) = ac[ct][dt];
    __syncthreads();

    const int tile = t >> 6;                   // re-partition: thread -> (tile, cell)
    const int ln   = t & 63;
    float v[4];
    #pragma unroll
    for (int r = 0; r < 4; ++r)
        v[r] = (red[0][tile][ln][r] + red[1][tile][ln][r])
             + (red[2][tile][ln][r] + red[3][tile][ln][r]);
    const int ct = tile >> 1, dt = tile & 1;
    const int qq = ln >> 4,  nn = ln & 15;
    // C-layout cell: G[c][d], c = c0+ct*16+qq*4+r, d = d0+dt*16+nn.
    // Frag dest: f = jt*8+kf = (by*2+dt)*8 + bx; slot = (ct*2+(qq>>1))*16+nn;
    // e = (qq&1)*4 + r.  (verified index math from R17)
    const int f    = (blockIdx.y * 2 + dt) * 8 + blockIdx.x;
    const int slot = (ct * 2 + (qq >> 1)) * 16 + nn;
    const int idx  = (f * 64 + slot) * 8 + (qq & 1) * 4;   // float index
    #pragma unroll
    for (int r = 0; r < 4; ++r)
        atomicAdd(&gPart[idx + r], v[r]);
}

// Per-row stats WITHOUT the NxN GEMM. Grid 256 x 512 thr: block = ONE i-tile
// (16 rows); 8 waves split the jt loop (2 each) -> 2 blocks/CU-equivalent
// wave load, 2 waves/SIMD (R18's 4-wave version was 1 wave/SIMD).
// classSim = mfma(afrag, afrag) diag blocks (wave 0); Y = Xb@(Ghi+Glo) with
// G read from fp32 gPart and hi/lo-split in registers (R17 RNE arithmetic);
// SQ_i = sum_d Y[i][d]*x[i][d], S_i = sum_d s[d]*x[i][d].
// Then 1 thread/row (t<16) computes inter/thresh/posLoss/psum/nsum.
__global__ __launch_bounds__(512)
void rowstats_kernel(const float* __restrict__ X,
                     const unsigned short* __restrict__ Xf,
                     const float* __restrict__ gPart,
                     const float* __restrict__ sCol,
                     float* __restrict__ c40A, float* __restrict__ threshA,
                     float* __restrict__ posLossA,
                     float* __restrict__ rowPsum, float* __restrict__ rowNsum)
{
    __shared__ float csL[16][8];
    __shared__ float sqL[8][16], smL[8][16];
    const int t    = threadIdx.x;
    const int lane = t & 63;
    const int w    = t >> 6;          // 0..7
    const int q    = lane >> 4;
    const int n    = lane & 15;
    const int it   = blockIdx.x;
    const int i0   = it * 16;

    bf16x8 afrag[8];
    const unsigned short* ap = Xf + (size_t)it * 8 * 512 + lane * 8;
    #pragma unroll
    for (int kf = 0; kf < 8; ++kf)
        afrag[kf] = *reinterpret_cast<const bf16x8*>(ap + kf * 512);

    // classSim: self-tile sim (afrag works as both A and B fragment)
    if (w == 0) {
        f32x4 cac = {0.f, 0.f, 0.f, 0.f};
        #pragma unroll
        for (int kf = 0; kf < 8; ++kf)
            cac = __builtin_amdgcn_mfma_f32_16x16x32_bf16(afrag[kf], afrag[kf], cac, 0, 0, 0);
        #pragma unroll
        for (int r = 0; r < 4; ++r) {
            int row = q * 4 + r;
            if (((row ^ n) >> 3) == 0) csL[row][n & 7] = cac[r];
        }
    }

    float sqa[4] = {0.f, 0.f, 0.f, 0.f};
    float sma[4] = {0.f, 0.f, 0.f, 0.f};
    #pragma unroll
    for (int jj = 0; jj < 2; ++jj) {
        const int jt = w * 2 + jj;
        const float* gp = gPart + (size_t)jt * 8 * 512 + lane * 8;
        f32x4 y0 = {0.f, 0.f, 0.f, 0.f};
        f32x4 y1 = {0.f, 0.f, 0.f, 0.f};
        #pragma unroll
        for (int kf = 0; kf < 8; ++kf) {
            float4 ga = *reinterpret_cast<const float4*>(gp + kf * 512);
            float4 gb = *reinterpret_cast<const float4*>(gp + kf * 512 + 4);
            uint4 H, L;
            split_pair(ga.x, ga.y, H.x, L.x);
            split_pair(ga.z, ga.w, H.y, L.y);
            split_pair(gb.x, gb.y, H.z, L.z);
            split_pair(gb.z, gb.w, H.w, L.w);
            bf16x8 gh = *reinterpret_cast<bf16x8*>(&H);
            bf16x8 gl = *reinterpret_cast<bf16x8*>(&L);
            y0 = __builtin_amdgcn_mfma_f32_16x16x32_bf16(afrag[kf], gh, y0, 0, 0, 0);
            y1 = __builtin_amdgcn_mfma_f32_16x16x32_bf16(afrag[kf], gl, y1, 0, 0, 0);
        }
        int d = jt * 16 + n;
        float sd = sCol[d];
        #pragma unroll
        for (int r = 0; r < 4; ++r) {
            float xl = X[(i0 + q * 4 + r) * 256 + d];
            sqa[r] = fmaf(y0[r] + y1[r], xl, sqa[r]);
            sma[r] = fmaf(sd, xl, sma[r]);
        }
    }
    #pragma unroll
    for (int r = 0; r < 4; ++r) {
        float a = sqa[r], b = sma[r];
        #pragma unroll
        for (int m = 8; m >= 1; m >>= 1) {
            a += __shfl_xor(a, m);
            b += __shfl_xor(b, m);
        }
        if (n == 0) { sqL[w][q * 4 + r] = a; smL[w][q * 4 + r] = b; }
    }
    __syncthreads();

    if (t < 16) {
        const int i = i0 + t;
        const int self = i & 7;
        float cs[KCLS];
        #pragma unroll
        for (int m = 0; m < KCLS; ++m) cs[m] = csL[t][m];
        float sii = cs[self];
        float psum = 0.f, psq = 0.f, pmin = 1e30f;
        #pragma unroll
        for (int m = 0; m < KCLS; ++m) {
            if (m != self) {
                psum += cs[m];
                psq  += cs[m] * cs[m];
                pmin  = fminf(pmin, cs[m]);
            }
        }
        const float p = (float)(KCLS - 1);            // 7
        const float mneg = (float)(NROWS - KCLS);     // 4088
        float S  = ((smL[0][t] + smL[1][t]) + (smL[2][t] + smL[3][t]))
                 + ((smL[4][t] + smL[5][t]) + (smL[6][t] + smL[7][t]));
        float SQ = ((sqL[0][t] + sqL[1][t]) + (sqL[2][t] + sqL[3][t]))
                 + ((sqL[4][t] + sqL[5][t]) + (sqL[6][t] + sqL[7][t]));
        float nsum = S - psum - sii;
        float nsq  = SQ - psq - sii * sii;
        float pmean = psum / p;
        float pstd  = sqrtf(fmaxf(psq / p - pmean * pmean, 0.f));
        float nmean = nsum / mneg;
        float nstd  = sqrtf(fmaxf(nsq / mneg - nmean * nmean, 0.f));
        float inter = 0.8f * (nstd * pmean + pstd * nmean) / (pstd + nstd) + 0.1f;
        float pl = 0.f;
        #pragma unroll
        for (int m = 0; m < KCLS; ++m) {
            if (m != self) pl += softplus_poly(-10.f * (cs[m] - inter));
        }
        c40A[i]     = -40.f * inter;
        threshA[i]  = pmin - 0.05f;
        posLossA[i] = pl * (0.2f / p);
        rowPsum[i]  = psum;
        rowNsum[i]  = nsum;
    }
}

// Loss GEMM (R16 loop verbatim). Grid (16,32). Block: 4 waves; wave w ->
// i-tiles [bx*16+w*4, +4) (64 rows, A cached in regs). All waves sweep
// j-tiles [by*8,+8); B staged via LDS (global_load_lds, double-buffered).
// Prologue just loads precomputed -40*inter / thresh per row.
__global__ __launch_bounds__(256)
void loss_gemm_kernel(const unsigned short* __restrict__ Xf,
                      const float* __restrict__ c40A,
                      const float* __restrict__ threshA,
                      float* __restrict__ cntPart,
                      float* __restrict__ nlsPart)
{
    __shared__ __align__(16) unsigned short Bs[2][8][512];   // 2 x 8 KB
    __shared__ float c40L[256], threshL[256];

    const int t    = threadIdx.x;
    const int lane = t & 63;
    const int wave = t >> 6;
    const int quad = lane >> 4;
    const int n16  = lane & 15;
    const int it0  = blockIdx.x * 16 + wave * NT;
    const int i0   = it0 * 16;
    const int j0   = blockIdx.y * 128;
    const int jt0  = blockIdx.y * 8;

    // A fragments: NT i-tiles x 8 k-frags, coalesced 1-KB global loads
    bf16x8 afrag[NT][8];
    #pragma unroll
    for (int tt = 0; tt < NT; ++tt) {
        const unsigned short* ap = Xf + ((size_t)(it0 + tt) * 8) * 512 + lane * 8;
        #pragma unroll
        for (int kf = 0; kf < 8; ++kf)
            afrag[tt][kf] = *reinterpret_cast<const bf16x8*>(ap + kf * 512);
    }

    {   // slim prologue: 2 loads/row
        const int i = blockIdx.x * 256 + t;
        c40L[t]    = c40A[i];          // already -40*inter
        threshL[t] = threshA[i];
    }

    // stage B frags for j-tile jt into buffer buf: wave w loads frags 2w,2w+1
    auto stage = [&](int buf, int jt) {
        const unsigned short* src =
            Xf + ((size_t)(jt0 + jt) * 8 + wave * 2) * 512 + lane * 8;
        glds16(src,       &Bs[buf][wave * 2][0]);
        glds16(src + 512, &Bs[buf][wave * 2 + 1][0]);
    };

    stage(0, 0);
    __syncthreads();    // drains glds AND publishes c40L/threshL

    float accA[NT][4] = {};       // cnt
    float accB[NT][4] = {};       // nls
    float c40[NT][4], threshR[NT][4];
    int   icls[NT];
    #pragma unroll
    for (int tt = 0; tt < NT; ++tt) {
        icls[tt] = (i0 + tt * 16 + quad * 4) >> 3;
        int lbase = wave * 64 + tt * 16 + quad * 4;   // local row in block
        #pragma unroll
        for (int r = 0; r < 4; ++r) {
            c40[tt][r]     = c40L[lbase + r];
            threshR[tt][r] = threshL[lbase + r];
        }
    }

    int buf = 0;
    #pragma unroll 1
    for (int jt = 0; jt < 8; ++jt) {
        if (jt < 7) stage(buf ^ 1, jt + 1);

        bf16x8 bfr[8];
        #pragma unroll
        for (int kf = 0; kf < 8; ++kf)
            bfr[kf] = *reinterpret_cast<const bf16x8*>(&Bs[buf][kf][lane * 8]);

        f32x4 ac[NT];
        #pragma unroll
        for (int tt = 0; tt < NT; ++tt) ac[tt] = {0.f, 0.f, 0.f, 0.f};
        #pragma unroll
        for (int kf = 0; kf < 8; ++kf) {
            #pragma unroll
            for (int tt = 0; tt < NT; ++tt)
                ac[tt] = __builtin_amdgcn_mfma_f32_16x16x32_bf16(afrag[tt][kf], bfr[kf], ac[tt], 0, 0, 0);
        }

        const int jcls = (j0 + jt * 16 + n16) >> 3;
        #pragma unroll
        for (int tt = 0; tt < NT; ++tt) {
            const bool neg = (icls[tt] != jcls);
            #pragma unroll
            for (int r = 0; r < 4; ++r) {
                float s  = ac[tt][r];
                float sp = softplus_poly(fmaf(40.f, s, c40[tt][r]));
                float m  = (neg && s > threshR[tt][r]) ? 1.f : 0.f;
                accA[tt][r] += m;
                accB[tt][r] = fmaf(m, sp, accB[tt][r]);
            }
        }

        __syncthreads();    // drains glds for jt+1; frees buf for jt+2
        buf ^= 1;
    }

    // quad shuffle-reduce (16 lanes share rows) -> float4 partial stores
    #pragma unroll
    for (int tt = 0; tt < NT; ++tt) {
        #pragma unroll
        for (int r = 0; r < 4; ++r) {
            #pragma unroll
            for (int m = 8; m >= 1; m >>= 1) {
                accA[tt][r] += __shfl_xor(accA[tt][r], m);
                accB[tt][r] += __shfl_xor(accB[tt][r], m);
            }
        }
        if (n16 == 0) {
            int base = blockIdx.y * NROWS + i0 + tt * 16 + quad * 4;
            float4 va = {accA[tt][0], accA[tt][1], accA[tt][2], accA[tt][3]};
            float4 vb = {accB[tt][0], accB[tt][1], accB[tt][2], accB[tt][3]};
            *reinterpret_cast<float4*>(&cntPart[base]) = va;
            *reinterpret_cast<float4*>(&nlsPart[base]) = vb;
        }
    }
}

// 16 blocks x 256 threads; thread -> one row. Reduce cnt/nls partials ->
// rowLoss/rowInv, block-reduce 4 sums, last block combines -> out.
__global__ __launch_bounds__(256)
void finalAB_kernel(const float* __restrict__ cntPart,
                    const float* __restrict__ nlsPart,
                    const float* __restrict__ posLossA,
                    const float* __restrict__ rowPsum,
                    const float* __restrict__ rowNsum,
                    float* __restrict__ blkPart,      // 16*4 floats
                    unsigned int* __restrict__ counter,
                    float* __restrict__ out)
{
    const int t = threadIdx.x;
    const int i = blockIdx.x * 256 + t;

    float c = 0.f, n = 0.f;
    #pragma unroll
    for (int b = 0; b < NJB; ++b) {
        c += cntPart[b * NROWS + i];
        n += nlsPart[b * NROWS + i];
    }
    float loss = (c > 0.f) ? (posLossA[i] + 0.05f * n / c) : 0.f;
    float inv  = (c > 0.f) ? 0.f : 1.f;
    float pd   = rowPsum[i];
    float nd   = rowNsum[i];

    #pragma unroll
    for (int off = 32; off > 0; off >>= 1) {
        loss += __shfl_down(loss, off);
        inv  += __shfl_down(inv, off);
        pd   += __shfl_down(pd, off);
        nd   += __shfl_down(nd, off);
    }
    __shared__ float sl[4], si[4], sp[4], sq[4];
    int w = t >> 6;
    if ((t & 63) == 0) { sl[w] = loss; si[w] = inv; sp[w] = pd; sq[w] = nd; }
    __syncthreads();
    if (t == 0) {
        blkPart[blockIdx.x * 4 + 0] = sl[0] + sl[1] + sl[2] + sl[3];
        blkPart[blockIdx.x * 4 + 1] = si[0] + si[1] + si[2] + si[3];
        blkPart[blockIdx.x * 4 + 2] = sp[0] + sp[1] + sp[2] + sp[3];
        blkPart[blockIdx.x * 4 + 3] = sq[0] + sq[1] + sq[2] + sq[3];
        __threadfence();
        unsigned int old = atomicAdd(counter, 1u);
        sl[0] = (old == 15u) ? 1.f : 0.f;       // reuse LDS as flag
    }
    __syncthreads();
    if (sl[0] != 0.f && t < 64) {
        // last block: coherent read of all 64 partials (distinct addresses)
        float v = atomicAdd(&blkPart[t], 0.f);
        #pragma unroll
        for (int off = 4; off < 64; off <<= 1) v += __shfl_xor(v, off);
        // lanes 0..3 now hold totals: loss, inv, psum, nsum
        if (t == 0) out[0] = v / (float)NROWS;
        if (t == 1) out[1] = v / (float)NROWS;
        if (t == 2) out[2] = v / ((float)NROWS * (float)(KCLS - 1));
        if (t == 3) out[3] = v / ((float)NROWS * (float)(NROWS - KCLS));
    }
}

extern "C" void kernel_launch(void* const* d_in, const int* in_sizes, int n_in,
                              void* d_out, int out_size, void* d_ws, size_t ws_size,
                              hipStream_t stream)
{
    const float* X = (const float*)d_in[0];

    float* ws       = (float*)d_ws;
    float* cntPart  = ws;                                   // 32*4096
    float* nlsPart  = cntPart + NJB * NROWS;                // 32*4096
    float* sCol     = nlsPart + NJB * NROWS;                // 256
    float* c40A     = sCol + 256;                           // 4096
    float* threshA  = c40A + NROWS;                         // 4096
    float* posLossA = threshA + NROWS;                      // 4096
    float* rowPsum  = posLossA + NROWS;                     // 4096
    float* rowNsum  = rowPsum + NROWS;                      // 4096
    float* blkPart  = rowNsum + NROWS;                      // 64
    unsigned int* counter = (unsigned int*)(blkPart + 64);  // 1 (+pad)
    float* gPart    = (float*)(counter + 16);               // 65536 (256 KB)
    unsigned short* Xf = (unsigned short*)(gPart + 65536);  // 2 MB
    // total ws use: ~3.4 MB; counter+sCol+gPart zeroed by convert

    convert_kernel<<<512, 256, 0, stream>>>(X, Xf, counter, sCol, gPart);

    gram_kernel<<<dim3(8, 8, 8), 256, 0, stream>>>(X, gPart, sCol);

    rowstats_kernel<<<256, 512, 0, stream>>>(X, Xf, gPart, sCol,
                                             c40A, threshA, posLossA,
                                             rowPsum, rowNsum);

    loss_gemm_kernel<<<dim3(16, 32), 256, 0, stream>>>(Xf, c40A, threshA,
                                                       cntPart, nlsPart);

    finalAB_kernel<<<16, 256, 0, stream>>>(cntPart, nlsPart, posLossA,
                                           rowPsum, rowNsum, blkPart, counter,
                                           (float*)d_out);
}